// Round 11
// baseline (142.131 us; speedup 1.0000x reference)
//
#include <hip/hip_runtime.h>

// ---------------------------------------------------------------------------
// PointAttentionEncoder1D, Round 11 = R10 with VALU instruction-count cuts.
// R10 post-mortem: VALU 71% + MFMA 21% = SIMD issue port saturated; the only
// lever is fewer instructions.
//  - v_cvt_pk_bf16_f32 (has_builtin-guarded, pkbf fallback): 1 inst/pair vs 3
//    for all bf16 packing (20 pairs/tile).
//  - B-frags from wave-private LDS slots (2 b128 writes once, 1 masked b128
//    read per tile) replacing 5 shfl + 8 cndmask + cmps per tile.
// Everything else R10 verbatim (66us kernel, verified).
// ---------------------------------------------------------------------------

constexpr int PPB = 15;
constexpr float LOG2E = 1.44269504088896340736f;

typedef __attribute__((ext_vector_type(8))) short bf8;   // K32 A/B frag
typedef __attribute__((ext_vector_type(4))) float f4;

__device__ __forceinline__ float lrelu(float v) { return fmaxf(v, 0.01f * v); }

// two f32 -> packed bf16x2 (lo = a, hi = b)
__device__ __forceinline__ unsigned int pkbf(float a, float b) {
#if __has_builtin(__builtin_amdgcn_cvt_pk_bf16_f32)
  typedef __attribute__((ext_vector_type(2))) __bf16 bf16x2;
  const bf16x2 r = __builtin_amdgcn_cvt_pk_bf16_f32(a, b);
  return __builtin_bit_cast(unsigned int, r);
#else
  const unsigned int ua = __builtin_bit_cast(unsigned int, a) + 0x8000u;
  const unsigned int ub = __builtin_bit_cast(unsigned int, b) + 0x8000u;
  return __builtin_amdgcn_perm(ub, ua, 0x07060302u);  // [b.hi16 : a.hi16]
#endif
}
__device__ __forceinline__ unsigned short us16(float a) {
  return (unsigned short)((__builtin_bit_cast(unsigned int, a) + 0x8000u) >> 16);
}
__device__ __forceinline__ bf8 mkbf8(const f4& a, const f4& b) {
  uint4 u;
  u.x = pkbf(a[0], a[1]); u.y = pkbf(a[2], a[3]);
  u.z = pkbf(b[0], b[1]); u.w = pkbf(b[2], b[3]);
  return __builtin_bit_cast(bf8, u);
}
__device__ __forceinline__ float exp2fast(float x) {
#if __has_builtin(__builtin_amdgcn_exp2f)
  return __builtin_amdgcn_exp2f(x);
#else
  float r; asm("v_exp_f32 %0, %1" : "=v"(r) : "v"(x)); return r;
#endif
}
__device__ __forceinline__ f4 mfma32(bf8 a, bf8 b, f4 c) {
  return __builtin_amdgcn_mfma_f32_16x16x32_bf16(a, b, c, 0, 0, 0);
}

// chunk-pair slot order: frag element (q, j) holds logical k = slotk(q,j)
__device__ __forceinline__ int slotk(int q, int j) {
  return (j < 4) ? (q * 4 + j) : (16 + q * 4 + (j - 4));
}

// ---------------- virtual weight matrices (proven R5-R10) -------------------
// input row = [x(3) | fea(3) | c(3) | 1 | 0...]
__device__ __forceinline__ float w1v(const float* mw1, const float* mb1,
                                     int s, int k, int n) {
  const int cb = n >> 4, cc = n & 15;
  const int sk = s ? 1 : 3, sv = s ? 2 : 4;
  if (k < 3)  return cb == 0 ? mw1[sk * 48 + k * 16 + cc]
                   : (cb == 1 ? mw1[sv * 48 + k * 16 + cc] : 0.f);
  if (k < 6)  return cb == 2 ? mw1[5 * 48 + (k - 3) * 16 + cc] : 0.f;
  if (k < 9)  return cb == 3 ? mw1[0 * 48 + (k - 6) * 16 + cc] : 0.f;
  if (k == 9) {
    const int m = (cb == 0) ? sk : (cb == 1) ? sv : (cb == 2) ? 5 : 0;
    return mb1[m * 16 + cc];
  }
  return 0.f;
}
__device__ __forceinline__ float w2v(const float* mw2, int s, int k, int n) {
  const int sk = s ? 1 : 3, sv = s ? 2 : 4;
  if (n < 32) {  // w = q - k + pos
    if (k < 16)            return -mw2[sk * 512 + k * 32 + n];
    if (k >= 32 && k < 48) return  mw2[5 * 512 + (k - 32) * 32 + n];
    if (k >= 48)           return  mw2[0 * 512 + (k - 48) * 32 + n];
    return 0.f;
  } else {       // vp = v + pos
    const int cc = n - 32;
    if (k >= 16 && k < 32) return mw2[sv * 512 + (k - 16) * 32 + cc];
    if (k >= 32 && k < 48) return mw2[5 * 512 + (k - 32) * 32 + cc];
    return 0.f;
  }
}

// ws16 (shorts), all K32 frags of 512 shorts, element [f*512 + lane*8 + j]:
//  [0,4096)      W1^T  f = s*4+c        k = q*8+j (matches bx layout)
//  [4096,12288)  W2^T  f = 8+s*8+mc*2+kc2   k = kc2*32+slotk, n = mc*16+l
//  [12288,14336) WP1^T f = 24+mc            k = slotk,        n = mc*16+l
//  [14336,16384) WP2^T f = 28+mc2*2+kc2     k = kc2*32+slotk, n = mc2*16+l, *LOG2E
// wsf (floats @ byte 32768): [bw_o(32)|bvp_o(32)|bw_c(32)|bvp_c(32)]
__global__ void prep_kernel(const float* __restrict__ mw1, const float* __restrict__ mb1,
                            const float* __restrict__ mw2, const float* __restrict__ mb2,
                            const float* __restrict__ ww1, const float* __restrict__ ww2,
                            unsigned short* __restrict__ ws16, float* __restrict__ wsf) {
  const int tid = blockIdx.x * 256 + threadIdx.x;
  const int lane = tid & 63, q = lane >> 4, l = lane & 15;
  if (tid < 2048) {
    const int f = tid >> 6;
    for (int j = 0; j < 8; j++) {
      float v;
      if (f < 8) {
        const int s = f >> 2, c = f & 3;
        v = w1v(mw1, mb1, s, q * 8 + j, c * 16 + l);
      } else if (f < 24) {
        const int g = f - 8, s = g >> 3, mc = (g >> 1) & 3, kc2 = g & 1;
        v = w2v(mw2, s, kc2 * 32 + slotk(q, j), mc * 16 + l);
      } else if (f < 28) {
        const int mc = f - 24;
        v = ww1[slotk(q, j) * 64 + mc * 16 + l];
      } else {
        const int g = f - 28, mc2 = g >> 1, kc2 = g & 1;
        v = ww2[(kc2 * 32 + slotk(q, j)) * 32 + mc2 * 16 + l] * LOG2E;
      }
      ws16[f * 512 + lane * 8 + j] = us16(v);
    }
  } else if (tid < 2176) {
    const int t2 = tid - 2048, grp = t2 >> 5, cc = t2 & 31;
    float v;
    if (grp == 0)      v = mb2[cc] - mb2[96 + cc] + mb2[160 + cc];   // bw other
    else if (grp == 1) v = mb2[128 + cc] + mb2[160 + cc];            // bvp other
    else if (grp == 2) v = mb2[cc] - mb2[32 + cc] + mb2[160 + cc];   // bw center
    else               v = mb2[64 + cc] + mb2[160 + cc];             // bvp center
    wsf[grp * 32 + cc] = v;
  }
}

// ---------------- main kernel ----------------------------------------------
__global__ __launch_bounds__(256, 2) void point_attn_kernel(
    const float* __restrict__ center, const float* __restrict__ other,
    const float* __restrict__ wb1, const float* __restrict__ wb2,
    const unsigned short* __restrict__ ws16, const float* __restrict__ wsf,
    float* __restrict__ out, int P) {
  __shared__ float pr[256 * 36];      // products [row][ch], stride 36 dwords
  __shared__ uint4 bf_s[4][64][2];    // per-wave B-frag slots [wv][row][slot]

  const int t = threadIdx.x, lane = t & 63, wv = t >> 6;
  const int q = lane >> 4, l = lane & 15;

  // ---- stage this thread's row as packed B-slots in wave-private LDS ------
  // slot0 = k0..7 (q0 lanes), slot1 = k8..15 (q1 lanes); q>=2 lanes are zero.
  {
    const int isC = (t >= 240);
    const int pt = isC ? (t - 240) : (t >> 4);
    int p = blockIdx.x * PPB + pt;
    p = p < P ? p : P - 1;
    const float c0 = center[(size_t)p * 3 + 0];
    const float c1 = center[(size_t)p * 3 + 1];
    const float c2 = center[(size_t)p * 3 + 2];
    const float* op = other + ((size_t)p * 16 + (t & 15)) * 3;
    const float o0 = op[0], o1 = op[1], o2 = op[2];
    const float x0 = isC ? c0 : o0, x1 = isC ? c1 : o1, x2 = isC ? c2 : o2;
    const float g0 = c0 - x0, g1 = c1 - x1, g2 = c2 - x2;  // 0 for center rows
    uint4 s0v, s1v;
    s0v.x = pkbf(x0, x1); s0v.y = pkbf(x2, g0);
    s0v.z = pkbf(g1, g2); s0v.w = pkbf(c0, c1);
    s1v.x = pkbf(c2, 1.0f); s1v.y = 0u; s1v.z = 0u; s1v.w = 0u;
    bf_s[wv][lane][0] = s0v;
    bf_s[wv][lane][1] = s1v;
    // same-wave producer/consumer: compiler waitcnt suffices, no barrier
  }

  // ---- weight/bias registers ----
  bf8 W1[4], W2[4][2], P1[4], P2[2][2];
  f4 bw[2], bvp[2], b1f[4], b2f[2];

  auto loadSet = [&](int s) {
#pragma unroll
    for (int c = 0; c < 4; c++)
      W1[c] = *(const bf8*)(ws16 + ((s * 4 + c) * 512 + lane * 8));
#pragma unroll
    for (int mc = 0; mc < 4; mc++)
#pragma unroll
      for (int kc2 = 0; kc2 < 2; kc2++)
        W2[mc][kc2] = *(const bf8*)(ws16 + ((8 + s * 8 + mc * 2 + kc2) * 512 + lane * 8));
#pragma unroll
    for (int mc = 0; mc < 2; mc++) {
      bw[mc]  = *(const f4*)(wsf + s * 64 + mc * 16 + q * 4);
      bvp[mc] = *(const f4*)(wsf + s * 64 + 32 + mc * 16 + q * 4);
    }
  };

  loadSet(wv == 3 ? 1 : 0);
#pragma unroll
  for (int mc = 0; mc < 4; mc++)
    P1[mc] = *(const bf8*)(ws16 + ((24 + mc) * 512 + lane * 8));
#pragma unroll
  for (int mc2 = 0; mc2 < 2; mc2++)
#pragma unroll
    for (int kc2 = 0; kc2 < 2; kc2++)
      P2[mc2][kc2] = *(const bf8*)(ws16 + ((28 + mc2 * 2 + kc2) * 512 + lane * 8));
#pragma unroll
  for (int mc = 0; mc < 4; mc++) b1f[mc] = *(const f4*)(wb1 + mc * 16 + q * 4);
#pragma unroll
  for (int mc2 = 0; mc2 < 2; mc2++) {
    const f4 b = *(const f4*)(wb2 + mc2 * 16 + q * 4);
#pragma unroll
    for (int j = 0; j < 4; j++) b2f[mc2][j] = b[j] * LOG2E;
  }

  auto computeTile = [&](int T) {
    // B-frag: one exec-masked b128 read (q<2); q>=2 lanes hold zeros
    const int lr = ((T & 3) << 4) | l;
    uint4 bu = {0u, 0u, 0u, 0u};
    if (q < 2) bu = bf_s[wv][lr][q];
    const bf8 bx = __builtin_bit_cast(bf8, bu);
    const f4 fzero = {0.f, 0.f, 0.f, 0.f};

    // S1: H^T chunks (K32, bias folded in virtual k=9 row)
    f4 D1[4];
#pragma unroll
    for (int c = 0; c < 4; c++) {
      f4 D = mfma32(W1[c], bx, fzero);
#pragma unroll
      for (int j = 0; j < 4; j++) D1[c][j] = lrelu(D[j]);
    }
    const bf8 hlo = mkbf8(D1[0], D1[1]);
    const bf8 hhi = mkbf8(D1[2], D1[3]);

    // S2: [w|vp]^T = W2^T x H^T, bias in C operand
    f4 wq[2], vpv[2];
#pragma unroll
    for (int mc = 0; mc < 4; mc++) {
      f4 acc = (mc < 2) ? bw[mc] : bvp[mc - 2];
      acc = mfma32(W2[mc][0], hlo, acc);
      acc = mfma32(W2[mc][1], hhi, acc);
      if (mc < 2) wq[mc] = acc; else vpv[mc - 2] = acc;
    }
    const bf8 wB = mkbf8(wq[0], wq[1]);

    // S3: Hwp^T = WP1^T x w^T, bias in C
    f4 h2[4];
#pragma unroll
    for (int mc = 0; mc < 4; mc++) {
      f4 acc = mfma32(P1[mc], wB, b1f[mc]);
#pragma unroll
      for (int j = 0; j < 4; j++) h2[mc][j] = lrelu(acc[j]);
    }
    const bf8 h2lo = mkbf8(h2[0], h2[1]);
    const bf8 h2hi = mkbf8(h2[2], h2[3]);

    // S4: fw^T (log2 domain) = WP2^T x Hwp^T, bias in C
    f4 fw[2];
#pragma unroll
    for (int mc2 = 0; mc2 < 2; mc2++) {
      f4 acc = mfma32(P2[mc2][0], h2lo, b2f[mc2]);
      fw[mc2] = mfma32(P2[mc2][1], h2hi, acc);
    }

    // softmax over 32 channels of row l, base-2 domain, no max-subtraction
    float ex[2][4], sum = 0.f;
#pragma unroll
    for (int mc = 0; mc < 2; mc++)
#pragma unroll
      for (int j = 0; j < 4; j++) {
        ex[mc][j] = exp2fast(fw[mc][j]);
        sum += ex[mc][j];
      }
    sum += __shfl_xor(sum, 16);
    sum += __shfl_xor(sum, 32);
    const float inv = __builtin_amdgcn_rcpf(sum);

    f4 p0, p1;
#pragma unroll
    for (int j = 0; j < 4; j++) {
      p0[j] = ex[0][j] * inv * vpv[0][j];
      p1[j] = ex[1][j] * inv * vpv[1][j];
    }
    *(f4*)&pr[(T * 16 + l) * 36 + q * 4] = p0;        // channels q*4..
    *(f4*)&pr[(T * 16 + l) * 36 + 16 + q * 4] = p1;   // channels 16+q*4..
  };

  // wave 3 does the center tile (15) first with the center weight set
  computeTile(wv == 3 ? 15 : wv * 4);
  if (wv == 3) loadSet(0);
#pragma unroll
  for (int jj = 1; jj < 4; jj++)
    computeTile(wv == 3 ? (11 + jj) : (wv * 4 + jj));

  __syncthreads();

  // final reduce: 17 rows per point (16 other + 1 center), coalesced stores
  for (int u = t; u < 480; u += 256) {
    const int pp = u >> 5, c = u & 31;
    float s = pr[(240 + pp) * 36 + c];
#pragma unroll
    for (int r2 = 0; r2 < 16; r2++) s += pr[(pp * 16 + r2) * 36 + c];
    const int gp = blockIdx.x * PPB + pp;
    if (gp < P) out[(size_t)gp * 32 + c] = s;
  }
}

extern "C" void kernel_launch(void* const* d_in, const int* in_sizes, int n_in,
                              void* d_out, int out_size, void* d_ws, size_t ws_size,
                              hipStream_t stream) {
  const float* center = (const float*)d_in[0];
  const float* other  = (const float*)d_in[1];
  unsigned short* ws16 = (unsigned short*)d_ws;
  float* wsf = (float*)((char*)d_ws + 32768);

  prep_kernel<<<9, 256, 0, stream>>>(
      (const float*)d_in[2], (const float*)d_in[3],
      (const float*)d_in[4], (const float*)d_in[5],
      (const float*)d_in[6], (const float*)d_in[8], ws16, wsf);

  const int P = in_sizes[0] / 3;
  const int blocks = (P + PPB - 1) / PPB;
  point_attn_kernel<<<blocks, 256, 0, stream>>>(
      center, other,
      (const float*)d_in[7], (const float*)d_in[9],
      ws16, wsf, (float*)d_out, P);
}